// Round 10
// baseline (146.647 us; speedup 1.0000x reference)
//
#include <hip/hip_runtime.h>
#include <hip/hip_fp16.h>

#define N_NODES 100000
#define N_EDGES 3200000
#define IN_DIM 6
#define HID_DIM 32
#define LAT_DIM 16

#define NPB 128                      // nodes per bucket (dst >> 7)
#define NB 782                       // ceil(100000 / 128)
#define CAP 4800                     // bucket segment capacity (mean 4092, sigma 64)
#define AB_BLOCKS 512
#define CH ((N_EDGES + AB_BLOCKS - 1) / AB_BLOCKS)   // 6250 edges per place block
#define PL_T 512                     // threads in k_bplace

// ---------------- init bucket cursors to segment bases ----------------
__global__ void k_init(int* __restrict__ bcur) {
    int i = blockIdx.x * blockDim.x + threadIdx.x;
    if (i < NB) bcur[i] = i * CAP;
}

// ---------------- place edges: LDS counting-sort staging -> coalesced writes ----------------
__global__ void __launch_bounds__(PL_T) k_bplace(const int* __restrict__ src,
                                                 const int* __restrict__ dst,
                                                 int* __restrict__ bcur,
                                                 int* __restrict__ bedge, int E) {
    __shared__ int hist[NB];
    __shared__ int lbase[NB];
    __shared__ int gbase[NB];
    __shared__ int cur[NB];
    __shared__ int part[PL_T];
    __shared__ int stage[CH];
    __shared__ unsigned short sbkt[CH];
    int t = threadIdx.x;
    for (int i = t; i < NB; i += PL_T) { hist[i] = 0; cur[i] = 0; }
    __syncthreads();
    int beg = blockIdx.x * CH, end = min(beg + CH, E);
    // pass 1: block-local histogram (nt loads: stream-once data)
    for (int e = beg + t; e < end; e += PL_T)
        atomicAdd(&hist[__builtin_nontemporal_load(dst + e) >> 7], 1);
    __syncthreads();
    // exclusive scan of hist -> lbase (2 elems/thread)
    int i0 = 2 * t;
    int a = (i0 < NB) ? hist[i0] : 0;
    int b = (i0 + 1 < NB) ? hist[i0 + 1] : 0;
    part[t] = a + b;
    __syncthreads();
    for (int off = 1; off < PL_T; off <<= 1) {
        int v = (t >= off) ? part[t - off] : 0;
        __syncthreads();
        part[t] += v;
        __syncthreads();
    }
    int ex = (t == 0) ? 0 : part[t - 1];
    if (i0 < NB) lbase[i0] = ex;
    if (i0 + 1 < NB) lbase[i0 + 1] = ex + a;
    __syncthreads();
    // reserve global ranges per bucket (bcur pre-seeded to b*CAP)
    for (int i = t; i < NB; i += PL_T)
        gbase[i] = hist[i] ? atomicAdd(&bcur[i], hist[i]) : 0;
    __syncthreads();
    // pass 2: scatter into LDS staging, sorted by bucket
    for (int e = beg + t; e < end; e += PL_T) {
        int d = __builtin_nontemporal_load(dst + e);
        int s = __builtin_nontemporal_load(src + e);
        int bkt = d >> 7;
        int r = atomicAdd(&cur[bkt], 1);
        int pos = lbase[bkt] + r;
        stage[pos] = (s << 7) | (d & (NPB - 1));
        sbkt[pos] = (unsigned short)bkt;
    }
    __syncthreads();
    // stream out: coalesced within bucket runs; regular store (re-read by k_sort via L2)
    int total = end - beg;
    for (int j = t; j < total; j += PL_T) {
        int bkt = sbkt[j];
        bedge[gbase[bkt] + (j - lbase[bkt])] = stage[j];
    }
}

// ---------------- per-bucket counting sort -> (beg,end) CSR + dinv + xs(fp16) ----------------
__global__ void __launch_bounds__(256) k_sort(const int* __restrict__ bcur,
                                              const int* __restrict__ bedge,
                                              const float* __restrict__ x,
                                              int2* __restrict__ rowse,
                                              int* __restrict__ perm,
                                              float* __restrict__ dinv,
                                              __half* __restrict__ xs, int N) {
    int b = blockIdx.x;
    __shared__ int cnt[NPB], base[NPB], cur[NPB], scn[NPB];
    __shared__ float dvs[NPB];
    __shared__ int pstage[CAP];  // 19.2 KB
    int t = threadIdx.x;
    if (t < NPB) cnt[t] = 0;
    __syncthreads();
    int beg = b * CAP, end = bcur[b];
    int m = end - beg;
    for (int k = t; k < m; k += blockDim.x)
        atomicAdd(&cnt[bedge[beg + k] & (NPB - 1)], 1);
    __syncthreads();
    if (t < NPB) scn[t] = cnt[t];
    __syncthreads();
    for (int off = 1; off < NPB; off <<= 1) {
        int v = 0;
        if (t < NPB && t >= off) v = scn[t - off];
        __syncthreads();
        if (t < NPB) scn[t] += v;
        __syncthreads();
    }
    if (t < NPB) {
        int ex = scn[t] - cnt[t];  // exclusive
        base[t] = ex;
        cur[t] = 0;
        int node = (b << 7) + t;
        if (node < N) {
            float dv = rsqrtf((float)(cnt[t] + 1));  // +1 self-loop
            dvs[t] = dv;
            dinv[node] = dv;
            rowse[node] = make_int2(beg + ex, beg + ex + cnt[t]);
        }
    }
    __syncthreads();
    // scatter into LDS staging (cheap), then coalesced stream-out
    for (int k = t; k < m; k += blockDim.x) {
        int w = bedge[beg + k];
        int dl = w & (NPB - 1);
        int pos = base[dl] + atomicAdd(&cur[dl], 1);
        pstage[pos] = w >> 7;
    }
    __syncthreads();
    for (int k = t; k < m; k += blockDim.x)
        perm[beg + k] = pstage[k];
    // fused: xs[n][d] = fp16(x[n][d] * dinv[n]), padded to 8 halfs (16B rows)
    for (int i = t; i < NPB * 4; i += blockDim.x) {
        int nl = i >> 2, d2 = (i & 3) * 2;
        int node = (b << 7) + nl;
        if (node < N) {
            float dv = dvs[nl];
            float v0 = (d2 < IN_DIM) ? x[(size_t)node * IN_DIM + d2] * dv : 0.f;
            float v1 = (d2 + 1 < IN_DIM) ? x[(size_t)node * IN_DIM + d2 + 1] * dv : 0.f;
            *(__half2*)(xs + (size_t)node * 8 + d2) = __floats2half2_rn(v0, v1);
        }
    }
}

// ---------------- layer 1 fused: aggregate (no shfl) -> W1+relu -> W2 -> h2s (fp16) ----------------
__global__ void __launch_bounds__(256) k_agg1f(const int2* __restrict__ rowse,
                                               const int* __restrict__ perm,
                                               const __half* __restrict__ xs,
                                               const float* __restrict__ dinv,
                                               const float* __restrict__ b1,
                                               const float* __restrict__ W1,
                                               const float* __restrict__ W2,
                                               __half* __restrict__ h2s, int N) {
    __shared__ float w1[IN_DIM * HID_DIM];
    __shared__ float w2[HID_DIM * LAT_DIM];
    __shared__ float bsh[HID_DIM];
    __shared__ float ash[32][HID_DIM + 1];  // +1 pad: avoid bank conflict
    __shared__ float y[32][8];
    int t = threadIdx.x;
    for (int i = t; i < IN_DIM * HID_DIM; i += 256) w1[i] = W1[i];
    for (int i = t; i < HID_DIM * LAT_DIM; i += 256) w2[i] = W2[i];
    if (t < HID_DIM) bsh[t] = b1[t];
    int nl = t >> 3, p = t & 7;
    int node = blockIdx.x * 32 + nl;
    float acc = 0.f;
    if (node < N) {
        int2 se = rowse[node];
        // group-uniform perm[k] load (one request, HW broadcast; L1 sector reuse
        // across 8 consecutive k). Lane p gathers its own 2B of the 16B xs row.
        for (int k = se.x; k < se.y; ++k) {
            int s = perm[k];
            acc += __half2float(xs[(size_t)s * 8 + p]);
        }
        acc += __half2float(xs[(size_t)node * 8 + p]);  // self-loop
    }
    y[nl][p] = acc;
    __syncthreads();
    float dv = (node < N) ? dinv[node] : 0.f;
    if (node < N) {
        float yy[IN_DIM];
#pragma unroll
        for (int k = 0; k < IN_DIM; k++) yy[k] = y[nl][k];
        int c0 = p * 4;
#pragma unroll
        for (int q = 0; q < 4; q++) {
            float z = 0.f;
#pragma unroll
            for (int k = 0; k < IN_DIM; k++) z += yy[k] * w1[k * HID_DIM + c0 + q];
            ash[nl][c0 + q] = fmaxf(dv * z + bsh[c0 + q], 0.f);
        }
    }
    __syncthreads();
    if (node < N) {
        int c = p * 2;
        float z0 = 0.f, z1 = 0.f;
#pragma unroll
        for (int k = 0; k < HID_DIM; k++) {
            float a = ash[nl][k];
            z0 += a * w2[k * LAT_DIM + c];
            z1 += a * w2[k * LAT_DIM + c + 1];
        }
        __half2 h = __floats2half2_rn(dv * z0, dv * z1);
        *(__half2*)(h2s + (size_t)node * LAT_DIM + c) = h;
    }
}

// ---------------- layer-2 gather-aggregate + bias -> out: 8 lanes/node, no shfl ----------------
__global__ void k_agg2(const int2* __restrict__ rowse, const int* __restrict__ perm,
                       const __half* __restrict__ h2s, const float* __restrict__ dinv,
                       const float* __restrict__ b2, float* __restrict__ out, int N) {
    int t = blockIdx.x * blockDim.x + threadIdx.x;
    int node = t >> 3, p = t & 7;
    if (node >= N) return;
    int2 se = rowse[node];
    float2 acc = make_float2(0.f, 0.f);
    for (int k = se.x; k < se.y; ++k) {
        int s = perm[k];  // group-uniform load; lane p gathers its 4B of the 32B row
        __half2 h = *(const __half2*)(h2s + (size_t)s * LAT_DIM + p * 2);
        float2 f = __half22float2(h);
        acc.x += f.x; acc.y += f.y;
    }
    __half2 hh = *(const __half2*)(h2s + (size_t)node * LAT_DIM + p * 2);  // self-loop
    float2 hs = __half22float2(hh);
    float dv = dinv[node];
    float2 bb = *(const float2*)(b2 + p * 2);
    float2 o;
    o.x = dv * (acc.x + hs.x) + bb.x;
    o.y = dv * (acc.y + hs.y) + bb.y;
    *(float2*)(out + (size_t)node * LAT_DIM + p * 2) = o;
}

extern "C" void kernel_launch(void* const* d_in, const int* in_sizes, int n_in,
                              void* d_out, int out_size, void* d_ws, size_t ws_size,
                              hipStream_t stream) {
    const float* x  = (const float*)d_in[0];
    const int*   ei = (const int*)d_in[1];
    const float* W1 = (const float*)d_in[2];
    const float* b1 = (const float*)d_in[3];
    const float* W2 = (const float*)d_in[4];
    const float* b2 = (const float*)d_in[5];
    float* out = (float*)d_out;

    const int N = N_NODES, E = N_EDGES;
    const int* src = ei;       // edge_index[0]
    const int* dst = ei + E;   // edge_index[1]

    // workspace carve (256B aligned)
    char* ws = (char*)d_ws;
    size_t off = 0;
    auto take = [&](size_t bytes) -> void* {
        void* p = ws + off;
        off += (bytes + 255) & ~(size_t)255;
        return p;
    };
    int*    bcur  = (int*)take((size_t)NB * 4);
    int*    bedge = (int*)take((size_t)NB * CAP * 4);
    int*    perm  = (int*)take((size_t)NB * CAP * 4);
    int2*   rowse = (int2*)take((size_t)N * 8);
    float*  dinv  = (float*)take((size_t)N * 4);
    __half* xs    = (__half*)take((size_t)N * 8 * 2);
    __half* h2s   = (__half*)take((size_t)N * LAT_DIM * 2);

    const int B = 256;
    k_init<<<(NB + B - 1) / B, B, 0, stream>>>(bcur);
    k_bplace<<<AB_BLOCKS, PL_T, 0, stream>>>(src, dst, bcur, bedge, E);
    k_sort<<<NB, B, 0, stream>>>(bcur, bedge, x, rowse, perm, dinv, xs, N);
    k_agg1f<<<(N + 31) / 32, B, 0, stream>>>(rowse, perm, xs, dinv, b1, W1, W2, h2s, N);
    k_agg2<<<((N * 8) + B - 1) / B, B, 0, stream>>>(rowse, perm, h2s, dinv, b2, out, N);
}

// Round 11
// 105.205 us; speedup vs baseline: 1.3939x; 1.3939x over previous
//
#include <hip/hip_runtime.h>
#include <hip/hip_fp16.h>

#define N_NODES 100000
#define N_EDGES 3200000
#define IN_DIM 6
#define HID_DIM 32
#define LAT_DIM 16

#define NPB 128                      // nodes per bucket (dst >> 7)
#define NB 782                       // ceil(100000 / 128)
#define CAP 4800                     // bucket segment capacity (mean 4092, sigma 64)
#define AB_BLOCKS 512
#define CH ((N_EDGES + AB_BLOCKS - 1) / AB_BLOCKS)   // 6250 edges per place block
#define PL_T 512                     // threads in k_bplace
#define LP_CAP 2080                  // per-block perm stage (mean 1024, sigma 32)

// ---------------- init bucket cursors to segment bases ----------------
__global__ void k_init(int* __restrict__ bcur) {
    int i = blockIdx.x * blockDim.x + threadIdx.x;
    if (i < NB) bcur[i] = i * CAP;
}

// ---------------- place edges: LDS counting-sort staging -> coalesced writes ----------------
__global__ void __launch_bounds__(PL_T) k_bplace(const int* __restrict__ src,
                                                 const int* __restrict__ dst,
                                                 int* __restrict__ bcur,
                                                 int* __restrict__ bedge, int E) {
    __shared__ int hist[NB];
    __shared__ int lbase[NB];
    __shared__ int gbase[NB];
    __shared__ int cur[NB];
    __shared__ int part[PL_T];
    __shared__ int stage[CH];
    __shared__ unsigned short sbkt[CH];
    int t = threadIdx.x;
    for (int i = t; i < NB; i += PL_T) { hist[i] = 0; cur[i] = 0; }
    __syncthreads();
    int beg = blockIdx.x * CH, end = min(beg + CH, E);
    // pass 1: block-local histogram (nt loads: stream-once data)
    for (int e = beg + t; e < end; e += PL_T)
        atomicAdd(&hist[__builtin_nontemporal_load(dst + e) >> 7], 1);
    __syncthreads();
    // exclusive scan of hist -> lbase (2 elems/thread)
    int i0 = 2 * t;
    int a = (i0 < NB) ? hist[i0] : 0;
    int b = (i0 + 1 < NB) ? hist[i0 + 1] : 0;
    part[t] = a + b;
    __syncthreads();
    for (int off = 1; off < PL_T; off <<= 1) {
        int v = (t >= off) ? part[t - off] : 0;
        __syncthreads();
        part[t] += v;
        __syncthreads();
    }
    int ex = (t == 0) ? 0 : part[t - 1];
    if (i0 < NB) lbase[i0] = ex;
    if (i0 + 1 < NB) lbase[i0 + 1] = ex + a;
    __syncthreads();
    // reserve global ranges per bucket (bcur pre-seeded to b*CAP)
    for (int i = t; i < NB; i += PL_T)
        gbase[i] = hist[i] ? atomicAdd(&bcur[i], hist[i]) : 0;
    __syncthreads();
    // pass 2: scatter into LDS staging, sorted by bucket
    for (int e = beg + t; e < end; e += PL_T) {
        int d = __builtin_nontemporal_load(dst + e);
        int s = __builtin_nontemporal_load(src + e);
        int bkt = d >> 7;
        int r = atomicAdd(&cur[bkt], 1);
        int pos = lbase[bkt] + r;
        stage[pos] = (s << 7) | (d & (NPB - 1));
        sbkt[pos] = (unsigned short)bkt;
    }
    __syncthreads();
    // stream out: coalesced within bucket runs; regular store (re-read by k_sort via L2)
    int total = end - beg;
    for (int j = t; j < total; j += PL_T) {
        int bkt = sbkt[j];
        bedge[gbase[bkt] + (j - lbase[bkt])] = stage[j];
    }
}

// ---------------- per-bucket counting sort -> (beg,end) CSR + dinv + xs(fp16) ----------------
__global__ void __launch_bounds__(256) k_sort(const int* __restrict__ bcur,
                                              const int* __restrict__ bedge,
                                              const float* __restrict__ x,
                                              int2* __restrict__ rowse,
                                              int* __restrict__ perm,
                                              float* __restrict__ dinv,
                                              __half* __restrict__ xs, int N) {
    int b = blockIdx.x;
    __shared__ int cnt[NPB], base[NPB], cur[NPB], scn[NPB];
    __shared__ float dvs[NPB];
    __shared__ int pstage[CAP];  // 19.2 KB
    int t = threadIdx.x;
    if (t < NPB) cnt[t] = 0;
    __syncthreads();
    int beg = b * CAP, end = bcur[b];
    int m = end - beg;
    for (int k = t; k < m; k += blockDim.x)
        atomicAdd(&cnt[bedge[beg + k] & (NPB - 1)], 1);
    __syncthreads();
    if (t < NPB) scn[t] = cnt[t];
    __syncthreads();
    for (int off = 1; off < NPB; off <<= 1) {
        int v = 0;
        if (t < NPB && t >= off) v = scn[t - off];
        __syncthreads();
        if (t < NPB) scn[t] += v;
        __syncthreads();
    }
    if (t < NPB) {
        int ex = scn[t] - cnt[t];  // exclusive
        base[t] = ex;
        cur[t] = 0;
        int node = (b << 7) + t;
        if (node < N) {
            float dv = rsqrtf((float)(cnt[t] + 1));  // +1 self-loop
            dvs[t] = dv;
            dinv[node] = dv;
            rowse[node] = make_int2(beg + ex, beg + ex + cnt[t]);
        }
    }
    __syncthreads();
    // scatter into LDS staging (cheap), then coalesced stream-out
    for (int k = t; k < m; k += blockDim.x) {
        int w = bedge[beg + k];
        int dl = w & (NPB - 1);
        int pos = base[dl] + atomicAdd(&cur[dl], 1);
        pstage[pos] = w >> 7;
    }
    __syncthreads();
    for (int k = t; k < m; k += blockDim.x)
        perm[beg + k] = pstage[k];
    // fused: xs[n][d] = fp16(x[n][d] * dinv[n]), padded to 8 halfs (16B rows)
    for (int i = t; i < NPB * 4; i += blockDim.x) {
        int nl = i >> 2, d2 = (i & 3) * 2;
        int node = (b << 7) + nl;
        if (node < N) {
            float dv = dvs[nl];
            float v0 = (d2 < IN_DIM) ? x[(size_t)node * IN_DIM + d2] * dv : 0.f;
            float v1 = (d2 + 1 < IN_DIM) ? x[(size_t)node * IN_DIM + d2 + 1] * dv : 0.f;
            *(__half2*)(xs + (size_t)node * 8 + d2) = __floats2half2_rn(v0, v1);
        }
    }
}

// ---------------- layer 1 fused: MLP-8 gather -> W1+relu -> W2 -> h2s (fp16) ----------------
// 3125 blocks x 256 threads; 32 nodes/block (N = 3125*32 exactly); 8 lanes/node.
__global__ void __launch_bounds__(256) k_agg1f(const int2* __restrict__ rowse,
                                               const int* __restrict__ perm,
                                               const __half* __restrict__ xs,
                                               const float* __restrict__ dinv,
                                               const float* __restrict__ b1,
                                               const float* __restrict__ W1,
                                               const float* __restrict__ W2,
                                               __half* __restrict__ h2s) {
    __shared__ float w1[IN_DIM * HID_DIM];
    __shared__ float w2[HID_DIM * LAT_DIM];
    __shared__ float bsh[HID_DIM];
    __shared__ float ash[32][HID_DIM + 1];
    __shared__ float y[32][8];
    __shared__ int lperm[LP_CAP];
    int t = threadIdx.x;
    for (int i = t; i < IN_DIM * HID_DIM; i += 256) w1[i] = W1[i];
    for (int i = t; i < HID_DIM * LAT_DIM; i += 256) w2[i] = W2[i];
    if (t < HID_DIM) bsh[t] = b1[t];
    int nl = t >> 3, p = t & 7;
    int n0 = blockIdx.x * 32;
    int node = n0 + nl;
    int gbeg = rowse[n0].x;
    int gend = rowse[n0 + 31].y;   // contiguous: 32 nodes never span a bucket
    int m = gend - gbeg;
    int2 se = rowse[node];
    float acc = 0.f;
    if (m <= LP_CAP) {
        for (int i = t; i < m; i += 256) lperm[i] = perm[gbeg + i];
        __syncthreads();
        int k = se.x - gbeg, lend = se.y - gbeg;
        for (; k + 8 <= lend; k += 8) {
            int s0 = lperm[k], s1 = lperm[k + 1], s2 = lperm[k + 2], s3 = lperm[k + 3];
            int s4 = lperm[k + 4], s5 = lperm[k + 5], s6 = lperm[k + 6], s7 = lperm[k + 7];
            __half g0 = xs[(size_t)s0 * 8 + p], g1 = xs[(size_t)s1 * 8 + p];
            __half g2 = xs[(size_t)s2 * 8 + p], g3 = xs[(size_t)s3 * 8 + p];
            __half g4 = xs[(size_t)s4 * 8 + p], g5 = xs[(size_t)s5 * 8 + p];
            __half g6 = xs[(size_t)s6 * 8 + p], g7 = xs[(size_t)s7 * 8 + p];
            acc += __half2float(g0) + __half2float(g1) + __half2float(g2) + __half2float(g3)
                 + __half2float(g4) + __half2float(g5) + __half2float(g6) + __half2float(g7);
        }
        for (; k < lend; ++k) acc += __half2float(xs[(size_t)lperm[k] * 8 + p]);
    } else {
        __syncthreads();  // match barrier
        int k = se.x;
        for (; k + 8 <= se.y; k += 8) {
            int s0 = perm[k], s1 = perm[k + 1], s2 = perm[k + 2], s3 = perm[k + 3];
            int s4 = perm[k + 4], s5 = perm[k + 5], s6 = perm[k + 6], s7 = perm[k + 7];
            acc += __half2float(xs[(size_t)s0 * 8 + p]) + __half2float(xs[(size_t)s1 * 8 + p])
                 + __half2float(xs[(size_t)s2 * 8 + p]) + __half2float(xs[(size_t)s3 * 8 + p])
                 + __half2float(xs[(size_t)s4 * 8 + p]) + __half2float(xs[(size_t)s5 * 8 + p])
                 + __half2float(xs[(size_t)s6 * 8 + p]) + __half2float(xs[(size_t)s7 * 8 + p]);
        }
        for (; k < se.y; ++k) acc += __half2float(xs[(size_t)perm[k] * 8 + p]);
    }
    acc += __half2float(xs[(size_t)node * 8 + p]);  // self-loop
    y[nl][p] = acc;
    __syncthreads();
    float dv = dinv[node];
    {
        float yy[IN_DIM];
#pragma unroll
        for (int k = 0; k < IN_DIM; k++) yy[k] = y[nl][k];
        int c0 = p * 4;
#pragma unroll
        for (int q = 0; q < 4; q++) {
            float z = 0.f;
#pragma unroll
            for (int k = 0; k < IN_DIM; k++) z += yy[k] * w1[k * HID_DIM + c0 + q];
            ash[nl][c0 + q] = fmaxf(dv * z + bsh[c0 + q], 0.f);
        }
    }
    __syncthreads();
    {
        int c = p * 2;
        float z0 = 0.f, z1 = 0.f;
#pragma unroll
        for (int k = 0; k < HID_DIM; k++) {
            float a = ash[nl][k];
            z0 += a * w2[k * LAT_DIM + c];
            z1 += a * w2[k * LAT_DIM + c + 1];
        }
        __half2 h = __floats2half2_rn(dv * z0, dv * z1);
        *(__half2*)(h2s + (size_t)node * LAT_DIM + c) = h;
    }
}

// ---------------- layer-2: MLP-8 gather + bias -> out; 32 nodes/block, 8 lanes/node ----------------
__global__ void __launch_bounds__(256) k_agg2(const int2* __restrict__ rowse,
                                              const int* __restrict__ perm,
                                              const __half* __restrict__ h2s,
                                              const float* __restrict__ dinv,
                                              const float* __restrict__ b2,
                                              float* __restrict__ out) {
    __shared__ int lperm[LP_CAP];
    int t = threadIdx.x;
    int n0 = blockIdx.x * 32;
    int node = n0 + (t >> 3), p = t & 7;
    int gbeg = rowse[n0].x;
    int gend = rowse[n0 + 31].y;
    int m = gend - gbeg;
    int2 se = rowse[node];
    float2 acc = make_float2(0.f, 0.f);
    if (m <= LP_CAP) {
        for (int i = t; i < m; i += 256) lperm[i] = perm[gbeg + i];
        __syncthreads();
        int k = se.x - gbeg, lend = se.y - gbeg;
        for (; k + 8 <= lend; k += 8) {
            int s0 = lperm[k], s1 = lperm[k + 1], s2 = lperm[k + 2], s3 = lperm[k + 3];
            int s4 = lperm[k + 4], s5 = lperm[k + 5], s6 = lperm[k + 6], s7 = lperm[k + 7];
            __half2 g0 = *(const __half2*)(h2s + (size_t)s0 * LAT_DIM + p * 2);
            __half2 g1 = *(const __half2*)(h2s + (size_t)s1 * LAT_DIM + p * 2);
            __half2 g2 = *(const __half2*)(h2s + (size_t)s2 * LAT_DIM + p * 2);
            __half2 g3 = *(const __half2*)(h2s + (size_t)s3 * LAT_DIM + p * 2);
            __half2 g4 = *(const __half2*)(h2s + (size_t)s4 * LAT_DIM + p * 2);
            __half2 g5 = *(const __half2*)(h2s + (size_t)s5 * LAT_DIM + p * 2);
            __half2 g6 = *(const __half2*)(h2s + (size_t)s6 * LAT_DIM + p * 2);
            __half2 g7 = *(const __half2*)(h2s + (size_t)s7 * LAT_DIM + p * 2);
            float2 f0 = __half22float2(g0), f1 = __half22float2(g1);
            float2 f2 = __half22float2(g2), f3 = __half22float2(g3);
            float2 f4 = __half22float2(g4), f5 = __half22float2(g5);
            float2 f6 = __half22float2(g6), f7 = __half22float2(g7);
            acc.x += f0.x + f1.x + f2.x + f3.x + f4.x + f5.x + f6.x + f7.x;
            acc.y += f0.y + f1.y + f2.y + f3.y + f4.y + f5.y + f6.y + f7.y;
        }
        for (; k < lend; ++k) {
            float2 f = __half22float2(*(const __half2*)(h2s + (size_t)lperm[k] * LAT_DIM + p * 2));
            acc.x += f.x; acc.y += f.y;
        }
    } else {
        __syncthreads();  // match barrier
        for (int k = se.x; k < se.y; ++k) {
            float2 f = __half22float2(*(const __half2*)(h2s + (size_t)perm[k] * LAT_DIM + p * 2));
            acc.x += f.x; acc.y += f.y;
        }
    }
    float2 hs = __half22float2(*(const __half2*)(h2s + (size_t)node * LAT_DIM + p * 2));  // self
    float dv = dinv[node];
    float2 bb = *(const float2*)(b2 + p * 2);
    float2 o;
    o.x = dv * (acc.x + hs.x) + bb.x;
    o.y = dv * (acc.y + hs.y) + bb.y;
    *(float2*)(out + (size_t)node * LAT_DIM + p * 2) = o;
}

extern "C" void kernel_launch(void* const* d_in, const int* in_sizes, int n_in,
                              void* d_out, int out_size, void* d_ws, size_t ws_size,
                              hipStream_t stream) {
    const float* x  = (const float*)d_in[0];
    const int*   ei = (const int*)d_in[1];
    const float* W1 = (const float*)d_in[2];
    const float* b1 = (const float*)d_in[3];
    const float* W2 = (const float*)d_in[4];
    const float* b2 = (const float*)d_in[5];
    float* out = (float*)d_out;

    const int N = N_NODES, E = N_EDGES;
    const int* src = ei;       // edge_index[0]
    const int* dst = ei + E;   // edge_index[1]

    // workspace carve (256B aligned)
    char* ws = (char*)d_ws;
    size_t off = 0;
    auto take = [&](size_t bytes) -> void* {
        void* p = ws + off;
        off += (bytes + 255) & ~(size_t)255;
        return p;
    };
    int*    bcur  = (int*)take((size_t)NB * 4);
    int*    bedge = (int*)take((size_t)NB * CAP * 4);
    int*    perm  = (int*)take((size_t)NB * CAP * 4);
    int2*   rowse = (int2*)take((size_t)N * 8);
    float*  dinv  = (float*)take((size_t)N * 4);
    __half* xs    = (__half*)take((size_t)N * 8 * 2);
    __half* h2s   = (__half*)take((size_t)N * LAT_DIM * 2);

    const int B = 256;
    k_init<<<(NB + B - 1) / B, B, 0, stream>>>(bcur);
    k_bplace<<<AB_BLOCKS, PL_T, 0, stream>>>(src, dst, bcur, bedge, E);
    k_sort<<<NB, B, 0, stream>>>(bcur, bedge, x, rowse, perm, dinv, xs, N);
    k_agg1f<<<N / 32, B, 0, stream>>>(rowse, perm, xs, dinv, b1, W1, W2, h2s);
    k_agg2<<<N / 32, B, 0, stream>>>(rowse, perm, h2s, dinv, b2, out);
}